// Round 14
// baseline (44.341 us; speedup 1.0000x reference)
//
#include <hip/hip_runtime.h>
#include <math.h>

#define TT 1024
#define DD 128

static constexpr float kNegInf = -1e9f;

typedef __fp16 h2 __attribute__((ext_vector_type(2)));

__device__ __forceinline__ unsigned int pk16(float a, float b) {
  h2 v = __builtin_amdgcn_cvt_pkrtz(a, b);
  return __builtin_bit_cast(unsigned int, v);
}
__device__ __forceinline__ float dot2f(unsigned int a, unsigned int b, float c) {
#if __has_builtin(__builtin_amdgcn_fdot2)
  return __builtin_amdgcn_fdot2(__builtin_bit_cast(h2, a),
                                __builtin_bit_cast(h2, b), c, false);
#else
  h2 av = __builtin_bit_cast(h2, a), bv = __builtin_bit_cast(h2, b);
  return c + (float)av.x * (float)bv.x + (float)av.y * (float)bv.y;
#endif
}

// ---- K0: transpose f32 [d][j], f16 j-pair pack [jp][d], swj/bias ----
__global__ __launch_bounds__(256) void k_prep(const float* __restrict__ h,
                                              const float* __restrict__ w,
                                              const int* __restrict__ mk,
                                              float* __restrict__ hTf,
                                              unsigned int* __restrict__ hT16,
                                              float* __restrict__ swj,
                                              float* __restrict__ bias) {
  __shared__ __align__(16) float tile[32][132];
  __shared__ float wred[32][8];
  const int b  = blockIdx.x >> 5;
  const int jt = blockIdx.x & 31;
  const int tid = threadIdx.x;
  const float4* src = (const float4*)h + (size_t)(b * TT + jt * 32) * 32;
#pragma unroll
  for (int k = 0; k < 4; ++k) {
    int idx = k * 256 + tid;             // 0..1023
    float4 v = src[idx];
    int j = idx >> 5, c = idx & 31;
    *((float4*)&tile[j][c * 4]) = v;
  }
  __syncthreads();
  // hTf[d][j]
#pragma unroll
  for (int k = 0; k < 4; ++k) {
    int idx = k * 256 + tid;             // 0..1023
    int d = idx >> 3, jq = idx & 7;
    float4 v = {tile[jq * 4 + 0][d], tile[jq * 4 + 1][d],
                tile[jq * 4 + 2][d], tile[jq * 4 + 3][d]};
    *(float4*)&hTf[(size_t)(b * DD + d) * TT + jt * 32 + jq * 4] = v;
  }
  // hT16[jp][d]
#pragma unroll
  for (int k = 0; k < 2; ++k) {
    int idx = k * 256 + tid;             // 0..511
    int jp = idx >> 5, dq = idx & 31;
    uint4 wv;
    wv.x = pk16(tile[jp * 2][dq * 4 + 0], tile[jp * 2 + 1][dq * 4 + 0]);
    wv.y = pk16(tile[jp * 2][dq * 4 + 1], tile[jp * 2 + 1][dq * 4 + 1]);
    wv.z = pk16(tile[jp * 2][dq * 4 + 2], tile[jp * 2 + 1][dq * 4 + 2]);
    wv.w = pk16(tile[jp * 2][dq * 4 + 3], tile[jp * 2 + 1][dq * 4 + 3]);
    *(uint4*)&hT16[((size_t)(b * 512 + jt * 16 + jp)) * DD + dq * 4] = wv;
  }
  // wj
  {
    const int j = tid & 31, dg = tid >> 5;
    float p = 0.f;
#pragma unroll
    for (int e = 0; e < 16; e += 4) {
      float4 hv = *(const float4*)&tile[j][dg * 16 + e];
      float4 wv = *(const float4*)&w[dg * 16 + e];
      p += hv.x * wv.x + hv.y * wv.y + hv.z * wv.z + hv.w * wv.w;
    }
    wred[j][dg] = p;
  }
  __syncthreads();
  if (tid < 32) {
    const int row = b * TT + jt * 32 + tid;
    float a = 0.f;
#pragma unroll
    for (int e = 0; e < 8; ++e) a += wred[tid][e];
    const bool ok = (mk[row] != 0);
    swj[row]  = ok ? -a : 0.f;
    bias[row] = ok ? 0.f : kNegInf;
  }
}

// ---- K1: block = 4 rows x 512 j (half); thread = J4 x R2; 1024 blocks ----
__global__ __launch_bounds__(256, 4) void k_fused(
    const float* __restrict__ h, const float* __restrict__ hTf,
    const unsigned int* __restrict__ hT16,
    const float* __restrict__ swj, const float* __restrict__ bias,
    float* __restrict__ ctxpart, float2* __restrict__ mlpart) {
  __shared__ __align__(16) float A_lds[4][DD];       // 2 KB
  __shared__ __align__(16) unsigned int Pt[256][4];  // 4 KB [jp_local][row]
  __shared__ __align__(16) float ctxp[4][4][DD];     // 8 KB [slice][row][d]
  __shared__ float redm[4][2];                       // [wave][rr]
  __shared__ float redl[4][2];

  const int tid  = threadIdx.x;
  const int lane = tid & 63;
  const int wv   = tid >> 6;
  const int rg   = blockIdx.x & 511;          // rowgroup: 4 rows, spans batches
  const int jh   = blockIdx.x >> 9;           // j-half 0..1
  const int b    = rg >> 8;
  const int row0 = (rg & 255) * 4;            // row within batch

  // stage 4 A-rows into LDS
  {
    const float2 v = *(const float2*)(h + ((size_t)b * TT + row0) * DD + tid * 2);
    *(float2*)&A_lds[0][tid * 2] = v;
  }
  __syncthreads();

  // ---------------- phase 1: distances, J=4 x R=2, explicit dbuf --------
  const int jq = tid & 127;                   // j-quad within half
  const int rp = tid >> 7;                    // row-pair 0/1
  const int j  = jh * 512 + jq * 4;           // j within batch
  const float* Bb = hTf + (size_t)b * DD * TT + j;
  const float* Ar0 = &A_lds[rp * 2][0];
  const float* Ar1 = &A_lds[rp * 2 + 1][0];
  float acc[4][2];
#pragma unroll
  for (int u = 0; u < 4; ++u) { acc[u][0] = 0.f; acc[u][1] = 0.f; }

#define LOADB4(B, s) {                                        \
    B[0] = *(const float4*)(Bb + (size_t)((s) * 4 + 0) * TT); \
    B[1] = *(const float4*)(Bb + (size_t)((s) * 4 + 1) * TT); \
    B[2] = *(const float4*)(Bb + (size_t)((s) * 4 + 2) * TT); \
    B[3] = *(const float4*)(Bb + (size_t)((s) * 4 + 3) * TT); }

#define COMP4(B, s) {                                                  \
    const float4 A0 = *(const float4*)(Ar0 + (s) * 4);                 \
    const float4 A1 = *(const float4*)(Ar1 + (s) * 4);                 \
    _Pragma("unroll") for (int e = 0; e < 4; ++e) {                    \
      const float a0 = (e == 0) ? A0.x : (e == 1) ? A0.y               \
                       : (e == 2) ? A0.z : A0.w;                       \
      const float a1 = (e == 0) ? A1.x : (e == 1) ? A1.y               \
                       : (e == 2) ? A1.z : A1.w;                       \
      acc[0][0] += fabsf(a0 - B[e].x); acc[0][1] += fabsf(a1 - B[e].x);\
      acc[1][0] += fabsf(a0 - B[e].y); acc[1][1] += fabsf(a1 - B[e].y);\
      acc[2][0] += fabsf(a0 - B[e].z); acc[2][1] += fabsf(a1 - B[e].z);\
      acc[3][0] += fabsf(a0 - B[e].w); acc[3][1] += fabsf(a1 - B[e].w);\
    } }

  {
    float4 B0[4], B1[4];
    LOADB4(B0, 0);
#pragma unroll 1
    for (int s = 0; s < 16; ++s) {
      LOADB4(B1, 2 * s + 1);             // unconditional: 2s+1 <= 31
      COMP4(B0, 2 * s);
      if (s < 15) LOADB4(B0, 2 * s + 2);
      COMP4(B1, 2 * s + 1);
    }
  }

  // scores
  const float4 swv = *(const float4*)(swj + (size_t)b * TT + j);
  const float4 bvv = *(const float4*)(bias + (size_t)b * TT + j);
  float sc[4][2];
  sc[0][0] = fmaf(swv.x, acc[0][0], bvv.x);
  sc[0][1] = fmaf(swv.x, acc[0][1], bvv.x);
  sc[1][0] = fmaf(swv.y, acc[1][0], bvv.y);
  sc[1][1] = fmaf(swv.y, acc[1][1], bvv.y);
  sc[2][0] = fmaf(swv.z, acc[2][0], bvv.z);
  sc[2][1] = fmaf(swv.z, acc[2][1], bvv.z);
  sc[3][0] = fmaf(swv.w, acc[3][0], bvv.w);
  sc[3][1] = fmaf(swv.w, acc[3][1], bvv.w);

  // partial (this j-half) row max: wave reduce + 2-wave combine
  {
    float mm[2];
#pragma unroll
    for (int rr = 0; rr < 2; ++rr) {
      float m0 = fmaxf(fmaxf(sc[0][rr], sc[1][rr]),
                       fmaxf(sc[2][rr], sc[3][rr]));
#pragma unroll
      for (int off = 32; off; off >>= 1) m0 = fmaxf(m0, __shfl_xor(m0, off));
      mm[rr] = m0;
    }
    if (lane == 0) { redm[wv][0] = mm[0]; redm[wv][1] = mm[1]; }
  }
  __syncthreads();
  float M[2];
  M[0] = fmaxf(redm[rp * 2][0], redm[rp * 2 + 1][0]);
  M[1] = fmaxf(redm[rp * 2][1], redm[rp * 2 + 1][1]);

  // exp + pack P j-pairs + sums
  {
    float p[4][2];
    float ls[2] = {0.f, 0.f};
#pragma unroll
    for (int u = 0; u < 4; ++u)
#pragma unroll
      for (int rr = 0; rr < 2; ++rr) {
        p[u][rr] = __expf(sc[u][rr] - M[rr]);
        ls[rr] += p[u][rr];
      }
    Pt[jq * 2 + 0][rp * 2 + 0] = pk16(p[0][0], p[1][0]);
    Pt[jq * 2 + 1][rp * 2 + 0] = pk16(p[2][0], p[3][0]);
    Pt[jq * 2 + 0][rp * 2 + 1] = pk16(p[0][1], p[1][1]);
    Pt[jq * 2 + 1][rp * 2 + 1] = pk16(p[2][1], p[3][1]);
#pragma unroll
    for (int rr = 0; rr < 2; ++rr) {
#pragma unroll
      for (int off = 32; off; off >>= 1) ls[rr] += __shfl_xor(ls[rr], off);
    }
    if (lane == 0) { redl[wv][0] = ls[0]; redl[wv][1] = ls[1]; }
  }
  __syncthreads();

  // write m/l partials
  if (tid < 4) {
    const int r = tid;
    const int w0 = (r >> 1) * 2, rr = r & 1;
    const float Mr = fmaxf(redm[w0][rr], redm[w0 + 1][rr]);
    const float Lr = redl[w0][rr] + redl[w0 + 1][rr];
    mlpart[jh * 2048 + rg * 4 + r] = make_float2(Mr, Lr);
  }

  // ---------------- PV: thread = (dpair 0..63) x (slice 0..3) ------------
  const int dp = tid & 63;
  const int s  = tid >> 6;                    // 64 jp each
  const unsigned int* Vp =
      hT16 + ((size_t)(b * 512 + jh * 256 + s * 64)) * DD + dp * 2;
  float cx[4][2];
#pragma unroll
  for (int r = 0; r < 4; ++r) { cx[r][0] = 0.f; cx[r][1] = 0.f; }
#pragma unroll 4
  for (int q = 0; q < 64; ++q) {
    const uint4 P = *(const uint4*)&Pt[s * 64 + q][0];    // broadcast
    const uint2 V = *(const uint2*)(Vp + (size_t)q * DD); // coalesced
    cx[0][0] = dot2f(P.x, V.x, cx[0][0]); cx[0][1] = dot2f(P.x, V.y, cx[0][1]);
    cx[1][0] = dot2f(P.y, V.x, cx[1][0]); cx[1][1] = dot2f(P.y, V.y, cx[1][1]);
    cx[2][0] = dot2f(P.z, V.x, cx[2][0]); cx[2][1] = dot2f(P.z, V.y, cx[2][1]);
    cx[3][0] = dot2f(P.w, V.x, cx[3][0]); cx[3][1] = dot2f(P.w, V.y, cx[3][1]);
  }
#pragma unroll
  for (int r = 0; r < 4; ++r)
    *(float2*)&ctxp[s][r][dp * 2] = make_float2(cx[r][0], cx[r][1]);
  __syncthreads();

  // reduce slices, write ctx partial
#pragma unroll
  for (int k = 0; k < 2; ++k) {
    const int idx = tid + k * 256;        // 0..511
    const int r = idx >> 7, d = idx & 127;
    ctxpart[((size_t)(jh * 2048 + rg * 4 + r)) * DD + d] =
        (ctxp[0][r][d] + ctxp[1][r][d]) + (ctxp[2][r][d] + ctxp[3][r][d]);
  }
}

// ---- K2: merge 2 j-half partials, normalize, write concat(h, ctx) ----
__global__ __launch_bounds__(256) void k_merge(const float* __restrict__ h,
                                               const float* __restrict__ ctxpart,
                                               const float2* __restrict__ mlpart,
                                               float* __restrict__ out) {
  const int row = blockIdx.x * 2 + (threadIdx.x >> 7);   // 0..2047
  const int d   = threadIdx.x & 127;

  const float2 ml0 = mlpart[row];
  const float2 ml1 = mlpart[2048 + row];
  const float M  = fmaxf(ml0.x, ml1.x);
  const float w0 = __expf(ml0.x - M), w1 = __expf(ml1.x - M);
  const float L  = fmaf(ml0.y, w0, ml1.y * w1);
  const float c  = ctxpart[(size_t)row * DD + d] * w0 +
                   ctxpart[(size_t)(2048 + row) * DD + d] * w1;
  out[(size_t)row * 256 + d]       = h[(size_t)row * DD + d];
  out[(size_t)row * 256 + 128 + d] = c / L;
}

extern "C" void kernel_launch(void* const* d_in, const int* in_sizes, int n_in,
                              void* d_out, int out_size, void* d_ws, size_t ws_size,
                              hipStream_t stream) {
  const float* h  = (const float*)d_in[0];
  const int*   mk = (const int*)d_in[1];
  const float* w  = (const float*)d_in[2];
  float* out = (float*)d_out;

  char* ws = (char*)d_ws;
  float*        swj  = (float*)ws;                              // 8 KB
  float*        bias = (float*)(ws + 8192);                     // 8 KB
  float*        hTf  = (float*)(ws + 16384);                    // 1 MB
  unsigned int* hT16 = (unsigned int*)(ws + 16384 + 1048576);   // 512 KB
  float*  ctxpart = (float*)(ws + 16384 + 1048576 + 524288);    // 2 MB
  float2* mlpart  = (float2*)(ws + 16384 + 1048576 + 524288 + 2097152);  // 32 KB

  hipLaunchKernelGGL(k_prep,  dim3(64),   dim3(256), 0, stream,
                     h, w, mk, hTf, hT16, swj, bias);
  hipLaunchKernelGGL(k_fused, dim3(1024), dim3(256), 0, stream,
                     h, hTf, hT16, swj, bias, ctxpart, mlpart);
  hipLaunchKernelGGL(k_merge, dim3(1024), dim3(256), 0, stream,
                     h, ctxpart, mlpart, out);
}